// Round 2
// baseline (118.486 us; speedup 1.0000x reference)
//
#include <hip/hip_runtime.h>
#include <math.h>

#define LOG2E 1.4426950408889634f

// ---------------------------------------------------------------------------
// Kernel 1: compress Z to uint8 in ws (Z in [1,95)) and zero the output
// (harness poisons d_out with 0xAA before every timed replay).
// ---------------------------------------------------------------------------
__global__ void __launch_bounds__(256)
zbl_prep(const int* __restrict__ Z, unsigned char* __restrict__ z8,
         float* __restrict__ out, int n_atoms, int out_n) {
    int i = blockIdx.x * blockDim.x + threadIdx.x;
    if (i < n_atoms) z8[i] = (unsigned char)Z[i];
    if (i < out_n)   out[i] = 0.0f;
}

// ---------------------------------------------------------------------------
// Kernel 2: 4 pairs per thread. Streaming loads are dwordx4; Z gathers are
// 1 byte from the 100 KB L2-resident z8 table; za = Z^|a_exp| from a 128-entry
// LDS table. Segmented reduction:
//   - thread-local run combine (interior runs commit directly; they cannot
//     cross a thread boundary),
//   - wave-64 segmented inclusive scan over the per-thread tail runs,
//   - boundary-correct commits (first run patched with prev lane's scanned c).
// Correctness relies on idx_i being globally sorted (non-decreasing), so keys
// within/between lanes are monotone.
// ---------------------------------------------------------------------------
__global__ void __launch_bounds__(256)
zbl_pairs4(const float* __restrict__ dist, const float* __restrict__ cut,
           const int* __restrict__ idx_i, const int* __restrict__ idx_j,
           const unsigned char* __restrict__ z8,
           const float* __restrict__ a_coef, const float* __restrict__ a_exp,
           const float* __restrict__ phi_c, const float* __restrict__ phi_e,
           const float* __restrict__ ke, const float* __restrict__ d2a,
           const float* __restrict__ e2m,
           float* __restrict__ out, int n) {
    __shared__ float za_tab[128];

    // Wave-uniform parameters (scalar loads).
    float aexp   = fabsf(a_exp[0]);
    float inv_ac = __fdividef(1.0f, fabsf(a_coef[0]));
    float c0 = fabsf(phi_c[0]), c1 = fabsf(phi_c[1]),
          c2 = fabsf(phi_c[2]), c3 = fabsf(phi_c[3]);
    float cnorm = __fdividef(1.0f, c0 + c1 + c2 + c3);
    c0 *= cnorm; c1 *= cnorm; c2 *= cnorm; c3 *= cnorm;
    // exp(-e*x) = exp2(-(e*log2e)*x)
    float e0 = fabsf(phi_e[0]) * LOG2E, e1 = fabsf(phi_e[1]) * LOG2E,
          e2 = fabsf(phi_e[2]) * LOG2E, e3 = fabsf(phi_e[3]) * LOG2E;
    float scale = ke[0] * e2m[0] * __fdividef(1.0f, d2a[0]);

    int t = threadIdx.x;
    if (t < 128) za_tab[t] = (t >= 1) ? exp2f(aexp * __log2f((float)t)) : 0.0f;
    __syncthreads();

    int gid = blockIdx.x * blockDim.x + t;
    int p0 = gid * 4;

    int   k[4];
    float v[4];

    if (p0 + 3 < n) {
        // full 4-pair path: dwordx4 streaming loads
        float4 d4 = ((const float4*)dist)[gid];
        float4 c4 = ((const float4*)cut)[gid];
        int4   i4 = ((const int4*)idx_i)[gid];
        int4   j4 = ((const int4*)idx_j)[gid];
        k[0] = i4.x; k[1] = i4.y; k[2] = i4.z; k[3] = i4.w;

        int zi0 = (int)z8[i4.x], zi1 = (int)z8[i4.y],
            zi2 = (int)z8[i4.z], zi3 = (int)z8[i4.w];
        int zj0 = (int)z8[j4.x], zj1 = (int)z8[j4.y],
            zj2 = (int)z8[j4.z], zj3 = (int)z8[j4.w];

        float arg0 = d4.x * (za_tab[zi0] + za_tab[zj0]) * inv_ac;
        float arg1 = d4.y * (za_tab[zi1] + za_tab[zj1]) * inv_ac;
        float arg2 = d4.z * (za_tab[zi2] + za_tab[zj2]) * inv_ac;
        float arg3 = d4.w * (za_tab[zi3] + za_tab[zj3]) * inv_ac;

        float phi0 = c0 * exp2f(-e0 * arg0) + c1 * exp2f(-e1 * arg0)
                   + c2 * exp2f(-e2 * arg0) + c3 * exp2f(-e3 * arg0);
        float phi1 = c0 * exp2f(-e0 * arg1) + c1 * exp2f(-e1 * arg1)
                   + c2 * exp2f(-e2 * arg1) + c3 * exp2f(-e3 * arg1);
        float phi2 = c0 * exp2f(-e0 * arg2) + c1 * exp2f(-e1 * arg2)
                   + c2 * exp2f(-e2 * arg2) + c3 * exp2f(-e3 * arg2);
        float phi3 = c0 * exp2f(-e0 * arg3) + c1 * exp2f(-e1 * arg3)
                   + c2 * exp2f(-e2 * arg3) + c3 * exp2f(-e3 * arg3);

        v[0] = scale * (float)(zi0 * zj0) * phi0 * c4.x * __fdividef(1.0f, d4.x);
        v[1] = scale * (float)(zi1 * zj1) * phi1 * c4.y * __fdividef(1.0f, d4.y);
        v[2] = scale * (float)(zi2 * zj2) * phi2 * c4.z * __fdividef(1.0f, d4.z);
        v[3] = scale * (float)(zi3 * zj3) * phi3 * c4.w * __fdividef(1.0f, d4.w);
    } else {
        // tail: scalar path; missing slots duplicate the previous key with
        // v=0 so they merge into the tail run harmlessly (keys stay sorted).
        #pragma unroll
        for (int q = 0; q < 4; ++q) {
            int p = p0 + q;
            if (p < n) {
                int ki = idx_i[p], jj = idx_j[p];
                int zi = (int)z8[ki], zj = (int)z8[jj];
                float d = dist[p];
                float arg = d * (za_tab[zi] + za_tab[zj]) * inv_ac;
                float phi = c0 * exp2f(-e0 * arg) + c1 * exp2f(-e1 * arg)
                          + c2 * exp2f(-e2 * arg) + c3 * exp2f(-e3 * arg);
                k[q] = ki;
                v[q] = scale * (float)(zi * zj) * phi * cut[p] * __fdividef(1.0f, d);
            } else {
                k[q] = (q > 0) ? k[q - 1] : -1;
                v[q] = 0.0f;
            }
        }
    }

    // --- thread-local run combine (unrolled, compile-time indices only) ---
    // run      = sum of current maximal run of equal keys
    // firstRun = sum of the run starting at element 0, if it ends in-thread
    // interior runs (start>0, end<3) are committed immediately: with sorted
    // keys they cannot extend into a neighboring thread.
    float run = v[0];
    float firstRun = 0.0f;
    bool  firstEnds = false;
    int   runStart = 0;
    #pragma unroll
    for (int q = 1; q < 4; ++q) {
        if (k[q] == k[q - 1]) {
            run += v[q];
        } else {
            if (runStart == 0) { firstRun = run; firstEnds = true; }
            else if (k[q - 1] >= 0) atomicAdd(out + k[q - 1], run);
            run = v[q];
            runStart = q;
        }
    }
    float c   = run;     // tail-run contribution
    int   key = k[3];    // tail-run key

    // --- wave-64 segmented inclusive scan over (key, c) ---
    int lane = t & 63;
    #pragma unroll
    for (int off = 1; off < 64; off <<= 1) {
        float ov = __shfl_up(c, (unsigned)off, 64);
        int   ok = __shfl_up(key, (unsigned)off, 64);
        if (lane >= off && ok == key) c += ov;
    }

    // Neighbor info for boundary commits.
    float prev_c   = __shfl_up(c, 1u, 64);
    int   prev_key = __shfl_up(key, 1u, 64);
    int   next_k0  = __shfl_down(k[0], 1u, 64);

    // Commit the first run if it ends inside this thread, patched with the
    // scanned contribution of preceding lanes in the same segment.
    if (k[0] >= 0 && firstEnds) {
        float tot = firstRun + ((lane > 0 && prev_key == k[0]) ? prev_c : 0.0f);
        atomicAdd(out + k[0], tot);
    }
    // Commit the tail segment at its last lane in the wave.
    bool tail = (lane == 63) || (next_k0 != key);
    if (key >= 0 && tail) atomicAdd(out + key, c);
}

extern "C" void kernel_launch(void* const* d_in, const int* in_sizes, int n_in,
                              void* d_out, int out_size, void* d_ws, size_t ws_size,
                              hipStream_t stream) {
    const int*   atomic_numbers = (const int*)  d_in[0];
    const float* distances      = (const float*)d_in[1];
    const float* cutoffs        = (const float*)d_in[2];
    const int*   idx_i          = (const int*)  d_in[3];
    const int*   idx_j          = (const int*)  d_in[4];
    const float* a_coefficient  = (const float*)d_in[5];
    const float* a_exponent     = (const float*)d_in[6];
    const float* phi_coeffs     = (const float*)d_in[7];
    const float* phi_exps       = (const float*)d_in[8];
    const float* ke             = (const float*)d_in[9];
    const float* d2a            = (const float*)d_in[10];
    const float* e2m            = (const float*)d_in[11];
    float* out = (float*)d_out;

    const int n_atoms = in_sizes[0];
    const int n_pairs = in_sizes[1];

    const int block = 256;
    const int n_threads = (n_pairs + 3) / 4;
    const int grid_pairs = (n_threads + block - 1) / block;
    const int grid_prep  = (((n_atoms > out_size) ? n_atoms : out_size) + block - 1) / block;

    // ws_size is ample (harness scratch); z8 needs only n_atoms bytes.
    unsigned char* z8 = (unsigned char*)d_ws;
    zbl_prep<<<grid_prep, block, 0, stream>>>(
        atomic_numbers, z8, out, n_atoms, out_size);
    zbl_pairs4<<<grid_pairs, block, 0, stream>>>(
        distances, cutoffs, idx_i, idx_j, z8,
        a_coefficient, a_exponent, phi_coeffs, phi_exps, ke, d2a, e2m,
        out, n_pairs);
}